// Round 11
// baseline (2340.016 us; speedup 1.0000x reference)
//
#include <hip/hip_runtime.h>
#include <math.h>

// ---- ws layout (u32/float offsets) ----
#define WS_CB2    0         // 192 (cb + b_hh folded for r,z)
#define WS_QE1    192       // 16384
#define WS_XE1    16576     // 65536
#define WS_G      82112     // 65536
#define WS_HW     147648    // 266240 -> ends 413888
#define WS_FW1H   413888    // 2048 u32 (8 frags)
#define WS_FWIHH  415936    // 6144 u32 (24 frags)
#define WS_FW2M   422080    // 6144
#define WS_FWHH   428224    // 6144 -> ends 434368
#define WS_GFLAG  442560    // 64 u32

// ---- dynamic LDS layout (u32 offsets) ----
#define OW2M   0        // 24 frags x 64 lanes x uint4 = 6144
#define OHROW  6144     // [8 slot][128 uint4 swizzled] = 4096
#define OGIR   10240    // [4][12][64] uint4 = 12288
#define OH32   22528    // [4][256 uint4 swizzled] = 4096
#define OCB2   26624    // 192 f32
#define OM1F   26816    // [2][16][72] ushort = 1152 u32
#define OHF    27968    // [2][16][72] ushort = 1152 u32
#define OFLG   29120    // 4 ints: 0=fH(W0) 1=fG(WH) 2=fR(stage) 3=fC(ship)
#define LDSW   29124
#define LDSBYTES (LDSW*4)

typedef _Float16 f16x8 __attribute__((ext_vector_type(8)));
typedef float    f32x4 __attribute__((ext_vector_type(4)));
union U4H { uint4 u; f16x8 h; };
union U4F { uint4 u; f32x4 f; };
__device__ inline f16x8 TOH(uint4 u){ U4H z; z.u=u; return z.h; }
__device__ inline unsigned PKH(float a, float b){
  union{_Float16 h[2]; unsigned u;} z; z.h[0]=(_Float16)a; z.h[1]=(_Float16)b; return z.u;
}
#define MFMA(a,b,c) __builtin_amdgcn_mfma_f32_16x16x32_f16((a),(b),(c),0,0,0)
#define POLLGE(P,T) do{ while(*(volatile int*)(P) < (T)) {} asm volatile("" ::: "memory"); }while(0)
#define AL64(p)    __hip_atomic_load((p), __ATOMIC_RELAXED, __HIP_MEMORY_SCOPE_AGENT)
#define AS64(p,v)  __hip_atomic_store((p), (v), __ATOMIC_RELAXED, __HIP_MEMORY_SCOPE_AGENT)

// ================= precompute (v10, unchanged) =================
__global__ __launch_bounds__(256) void kPrep(
    const int* __restrict__ q, const int* __restrict__ r,
    const float* __restrict__ x_emb, const float* __restrict__ q_emb,
    const float* __restrict__ init_h, const float* __restrict__ w1,
    const float* __restrict__ b1, const float* __restrict__ w2,
    const float* __restrict__ b2, const float* __restrict__ w_ih,
    const float* __restrict__ w_hh, const float* __restrict__ b_ih,
    const float* __restrict__ b_hh,
    float* __restrict__ ws, float* __restrict__ h_full)
{
  int idx = blockIdx.x*256 + threadIdx.x;
  unsigned* wsu = (unsigned*)ws;
  if (idx < 192) {
    int g = idx; float s = b_ih[g];
    for (int j=0;j<64;j++) s += b2[j]*w_ih[g*128+j];
    if (g < 128) s += b_hh[g];
    ws[WS_CB2+g] = s;
  } else if (idx < 16576) {
    int e = idx-192; int c = e>>6, i = e&63;
    float s = b1[i];
    for (int k=0;k<64;k++) s += q_emb[c*64+k]*w1[(64+k)*64+i];
    ws[WS_QE1+e] = s;
  } else if (idx < 82112) {
    int e = idx-16576; int bt = e>>6, i = e&63;
    int row = q[bt] + 256*r[bt];
    float s = b1[i];
    for (int k=0;k<64;k++) s += x_emb[row*64+k]*w1[(64+k)*64+i];
    ws[WS_XE1+e] = s;
  } else if (idx < 147648) {
    int e = idx-82112; int a = e>>8, cc = e&255;
    float s = 0.f;
    for (int d=0;d<64;d++) s += q_emb[a*64+d]*q_emb[cc*64+d];
    ws[WS_G+e] = s;
  } else if (idx < 409792) {
    int e = idx-147648; int bb = e>>14, cf = e&16383;
    h_full[(size_t)bb*65*16384 + cf] = init_h[cf];
  } else if (idx < 430272) {
    int e, tbl;
    if (idx < 411840)      { e = idx-409792; tbl=0; }
    else if (idx < 417984) { e = idx-411840; tbl=1; }
    else if (idx < 424128) { e = idx-417984; tbl=2; }
    else                   { e = idx-424128; tbl=3; }
    int f = e>>8, rem = e&255, lane = rem>>2, v = rem&3;
    int mt = f>>1, ks = f&1, li = lane&15, grp = lane>>4;
    int kg = ks*32 + grp*8 + v*2;
    float v0, v1;
    if (tbl==0){ int i = mt*16+li; v0 = w1[kg*64+i]; v1 = w1[(kg+1)*64+i];
      wsu[WS_FW1H+e] = PKH(v0,v1); }
    else if (tbl==1){ int g = mt*16+li; v0 = w_ih[g*128+64+kg]; v1 = w_ih[g*128+64+kg+1];
      wsu[WS_FWIHH+e] = PKH(v0,v1); }
    else if (tbl==2){ int g = mt*16+li; v0=0.f; v1=0.f;
      for (int j=0;j<64;j++){ float wij = w_ih[g*128+j];
        v0 += w2[kg*64+j]*wij; v1 += w2[(kg+1)*64+j]*wij; }
      wsu[WS_FW2M+e] = PKH(v0,v1); }
    else { int g = mt*16+li; v0 = w_hh[g*64+kg]; v1 = w_hh[g*64+kg+1];
      wsu[WS_FWHH+e] = PKH(v0,v1); }
  }
}

// ================= MFMA-batched wavefront v11 =================
// 64 WGs (one chain t each), 192 threads (3 waves), 1 WG/CU.
// W0: crit (24 MFMA + gates). WH: gi (56 MFMA). W2: coalesced I/O.
__global__ __launch_bounds__(192,1) void kW(
    const int* __restrict__ q, const float* __restrict__ b_hh,
    const float* __restrict__ init_h,
    float* __restrict__ ws, float* __restrict__ h_full)
{
  extern __shared__ unsigned lds[];
  const int bid = blockIdx.x;
  const int t = ((bid&7)<<3) | (bid>>3);
  const int tid = threadIdx.x, w = tid>>6, lane = tid&63;
  const int b = lane&15, grp = lane>>4;
  unsigned* wsu = (unsigned*)ws;
  unsigned* gflag = wsu + WS_GFLAG;
  int* FLG = (int*)&lds[OFLG];

  for (int k=tid; k<6144; k+=192) lds[OW2M+k] = wsu[WS_FW2M+k];
  for (int k=tid; k<192;  k+=192) lds[OCB2+k] = wsu[WS_CB2+k];
  for (int k=tid; k<1152; k+=192) lds[OHF+k] = 0;
  if (tid<4) FLG[tid]=0;
  __syncthreads();

  if (w==0){
    // ---------------- W0: critical GRU wave ----------------
    f16x8 wf[24];
    #pragma unroll
    for (int f=0; f<24; f++){ U4H z; z.u = ((const uint4*)(wsu+WS_FWHH))[f*64+lane]; wf[f]=z.h; }
    f32x4 bh[4], hv[4];
    #pragma unroll
    for (int mt=0; mt<4; mt++){
      #pragma unroll
      for (int e=0;e<4;e++){ bh[mt][e] = b_hh[128 + mt*16 + grp*4 + e]; hv[mt][e]=0.f; }
    }
    const ushort* hfp = (const ushort*)&lds[OHF];
    ushort* hop = (ushort*)&lds[OHF];
    for (int c=0;c<256;c++){
      POLLGE(&FLG[3], c-3);                    // h32 ring depth 4 (per-cell guard)
      POLLGE(&FLG[1], c+1);                    // gi[c] ready
      int hbase = ((c&1)^1)*1152 + b*72;
      f16x8 hb0 = TOH(*(const uint4*)&hfp[hbase + grp*8]);
      f16x8 hb1 = TOH(*(const uint4*)&hfp[hbase + 32 + grp*8]);
      f32x4 acc[12];
      #pragma unroll
      for (int mt=0; mt<12; mt++){
        f32x4 a = (f32x4){0.f,0.f,0.f,0.f};
        a = MFMA(wf[mt*2],   hb0, a);
        a = MFMA(wf[mt*2+1], hb1, a);
        acc[mt] = a;
      }
      const uint4* gip = (const uint4*)&lds[OGIR + (c&3)*3072];
      uint4* h32p = (uint4*)&lds[OH32 + (c&3)*1024];
      int obase = (c&1)*1152 + b*72;
      #pragma unroll
      for (int mt=0; mt<4; mt++){
        U4F gr,gz,gn;
        gr.u = gip[mt*64+lane]; gz.u = gip[(4+mt)*64+lane]; gn.u = gip[(8+mt)*64+lane];
        f32x4 r4 = acc[mt], z4 = acc[4+mt], n4 = acc[8+mt];
        f32x4 h4 = hv[mt];
        #pragma unroll
        for (int e=0;e<4;e++){
          float rg = 1.f/(1.f+__expf(-(gr.f[e]+r4[e])));
          float zg = 1.f/(1.f+__expf(-(gz.f[e]+z4[e])));
          float xn = gn.f[e] + rg*(n4[e]+bh[mt][e]);
          float e2 = __expf(2.f*xn);
          float ng = 1.f - 2.f/(e2+1.f);
          h4[e] = zg*h4[e] + (1.f-zg)*ng;
        }
        hv[mt] = h4;
        U4F hw_; hw_.f = h4;
        int idx = mt*64 + grp*16 + b;
        h32p[idx ^ ((idx>>4)&7)] = hw_.u;      // swizzled h32 (conflict-free)
        unsigned p0 = PKH(h4[0],h4[1]), p1 = PKH(h4[2],h4[3]);
        *(uint2*)&hop[obase + mt*16 + grp*4] = make_uint2(p0,p1);
      }
      asm volatile("s_waitcnt lgkmcnt(0)" ::: "memory");
      if (lane==0) *(volatile int*)&FLG[0] = c+1;
    }
  } else if (w==1){
    // ---------------- WH: gi helper wave ----------------
    f16x8 w1f[8], wif[24];
    #pragma unroll
    for (int f=0; f<8; f++){ U4H z; z.u = ((const uint4*)(wsu+WS_FW1H))[f*64+lane]; w1f[f]=z.h; }
    #pragma unroll
    for (int f=0; f<24; f++){ U4H z; z.u = ((const uint4*)(wsu+WS_FWIHH))[f*64+lane]; wif[f]=z.h; }
    f32x4 xr4[4];
    #pragma unroll
    for (int mt=0; mt<4; mt++)
      #pragma unroll
      for (int e=0;e<4;e++) xr4[mt][e] = ws[WS_XE1 + (b*64+t)*64 + mt*16 + grp*4 + e];
    const int qv = q[b*64 + t];
    // precomputed swizzled hrow offsets (uint4 units)
    const int i0 = grp*16 + b,        o0 = i0 ^ ((i0>>4)&7);
    const int i1 = 64 + grp*16 + b,   o1 = i1 ^ ((i1>>4)&7);
    const uint4* hrp = (const uint4*)&lds[OHROW];
    const uint4* w2p = (const uint4*)&lds[OW2M];
    ushort* m1p = (ushort*)&lds[OM1F];
    for (int s=0; s<256; s++){
      POLLGE(&FLG[0], s-3);                    // gi ring depth 4
      POLLGE(&FLG[2], s+1);                    // hrow staged
      f16x8 hb0 = TOH(hrp[(s&7)*128 + o0]);
      f16x8 hb1 = TOH(hrp[(s&7)*128 + o1]);
      int mbase = (s&1)*1152 + b*72;
      #pragma unroll
      for (int mt=0; mt<4; mt++){
        f32x4 a = (f32x4){0.f,0.f,0.f,0.f};
        a = MFMA(w1f[mt*2],   hb0, a);
        a = MFMA(w1f[mt*2+1], hb1, a);
        const f32x4 qe = *(const f32x4*)&ws[WS_QE1 + s*64 + mt*16 + grp*4];
        f32x4 ev = (qv==s) ? xr4[mt] : qe;
        unsigned p0 = PKH(fmaxf(a[0]+ev[0],0.f), fmaxf(a[1]+ev[1],0.f));
        unsigned p1 = PKH(fmaxf(a[2]+ev[2],0.f), fmaxf(a[3]+ev[3],0.f));
        *(uint2*)&m1p[mbase + mt*16 + grp*4] = make_uint2(p0,p1);
      }
      f16x8 mb0 = TOH(*(const uint4*)&m1p[mbase + grp*8]);
      f16x8 mb1 = TOH(*(const uint4*)&m1p[mbase + 32 + grp*8]);
      uint4* gop = (uint4*)&lds[OGIR + (s&3)*3072];
      #pragma unroll
      for (int mt=0; mt<12; mt++){
        U4F cbv; cbv.u = *(const uint4*)&lds[OCB2 + mt*16 + grp*4];
        f32x4 a = cbv.f;
        a = MFMA(wif[mt*2],   hb0, a);
        a = MFMA(wif[mt*2+1], hb1, a);
        a = MFMA(TOH(w2p[(mt*2)*64+lane]),   mb0, a);
        a = MFMA(TOH(w2p[(mt*2+1)*64+lane]), mb1, a);
        U4F o; o.f = a; gop[mt*64+lane] = o.u;
      }
      asm volatile("s_waitcnt lgkmcnt(0)" ::: "memory");
      if (lane==0) *(volatile int*)&FLG[1] = s+1;
    }
  } else {
    // ---------------- W2: coalesced I/O wave ----------------
    unsigned* gfp = gflag + (t-1);
    unsigned* gfc = gflag + t;
    unsigned long long* hf64 = (unsigned long long*)h_full;
    const int l31 = lane&31, hw_ = lane>>5;
    const size_t inU32  = (size_t)16384;          // per-(b,t) stride handled below
    unsigned gv = 0; int sp = 0;
    // per-lane constant decode for staging (ks,grp_w,w from l31)
    const int s_ks  = l31>>4, s_gp = (l31>>2)&3, s_w = l31&3;
    const int s_swz = (l31>>2)&7;
    // copyout decode
    const int c_mt = l31>>3, c_gp = (l31>>1)&3, c_e = 2*(l31&1);
    const int c_swz = (l31>>1)&7;

    for (int c=0; c<256; c++){
      // ---- stage rows (blocking to c+3) ----
      int lim = c+3; if (lim>255) lim=255;
      while (sp <= lim){
        POLLGE(&FLG[1], sp-7);                 // hrow ring depth 8
        if (t>0){
          while (gv < (unsigned)(sp+1)){
            gv = AL64(gfp);
            if (gv < (unsigned)(sp+1)) __builtin_amdgcn_s_sleep(1);
          }
        }
        #pragma unroll
        for (int k=0;k<8;k++){
          int bb = 2*k + hw_;
          int j = 2*l31;
          float f0, f1;
          if (t==0){
            f0 = init_h[sp*64 + j]; f1 = init_h[sp*64 + j + 1];
          } else {
            unsigned long long v = AL64(&hf64[(((size_t)(bb*65+t)<<14) + sp*64 + j)>>1]);
            union{unsigned long long q; float f[2];} cv; cv.q = v;
            f0 = cv.f[0]; f1 = cv.f[1];
          }
          int idx = s_ks*64 + s_gp*16 + bb;
          lds[OHROW + (sp&7)*512 + (idx ^ s_swz)*4 + s_w] = PKH(f0,f1);
        }
        asm volatile("s_waitcnt lgkmcnt(0)" ::: "memory");
        if (lane==0) *(volatile int*)&FLG[2] = sp+1;
        sp++;
      }
      // ---- copyout row c (coalesced 8B atomics) ----
      POLLGE(&FLG[0], c+1);
      unsigned long long vals[8];
      #pragma unroll
      for (int k=0;k<8;k++){
        int bb = 2*k + hw_;
        int idx = c_mt*64 + c_gp*16 + bb;
        vals[k] = *(const unsigned long long*)&lds[OH32 + (c&3)*1024 + (idx ^ c_swz)*4 + c_e];
      }
      asm volatile("s_waitcnt lgkmcnt(0)" ::: "memory");
      if (lane==0) *(volatile int*)&FLG[3] = c+1;   // h32/hop slot free
      #pragma unroll
      for (int k=0;k<8;k++){
        int bb = 2*k + hw_;
        int j = 2*l31;
        AS64(&hf64[(((size_t)(bb*65+t+1)<<14) + c*64 + j)>>1], vals[k]);
      }
      if ((c&3)==3){
        asm volatile("s_waitcnt vmcnt(0)" ::: "memory");
        if (lane==0) AS64(gfc, (unsigned)(c+1));
      }
    }
    (void)inU32;
  }
}

// ================= hw[b][u][c] = h_full[b][u][c][:] . out_w =================
__global__ __launch_bounds__(256) void kHw(const float* __restrict__ h_full,
    const float* __restrict__ out_w, float* __restrict__ hw)
{
  __shared__ float ow[64];
  if (threadIdx.x < 64) ow[threadIdx.x] = out_w[threadIdx.x];
  __syncthreads();
  const int blk = blockIdx.x, c = threadIdx.x;
  const float* hp = h_full + ((size_t)blk*256 + c)*64;
  float s = 0.f;
  #pragma unroll
  for (int f=0; f<64; f++) s += hp[f]*ow[f];
  hw[blk*256+c] = s;
}

// ================= readout =================
__global__ __launch_bounds__(256) void kY(const int* __restrict__ q,
    const float* __restrict__ ws, const float* __restrict__ bias,
    const float* __restrict__ theta, float* __restrict__ y)
{
  const float* G  = ws + WS_G;
  const float* hw = ws + WS_HW;
  const int b = blockIdx.x >> 2, tq = blockIdx.x & 3;
  const int c = threadIdx.x;
  __shared__ float siml[64][256];
  for (int u=0; u<64; u++) {
    int qq = q[b*64+u];
    siml[u][c] = G[qq*256+c];
  }
  __syncthreads();
  const float rate = __expf(theta[0]);
  const float bv = bias[c];
  const float* hwb = hw + b*65*256;
  for (int tt=0; tt<16; tt++) {
    const int t = tq*16+tt;
    float mx = -1e30f;
    for (int u=0; u<=t; u++) {
      float s = __expf(-rate*(float)(t-u))*siml[u][c];
      mx = fmaxf(mx, s);
    }
    float se = 0.f, sw = 0.f;
    for (int u=0; u<=t; u++) {
      float s = __expf(-rate*(float)(t-u))*siml[u][c];
      float e = __expf(s-mx);
      se += e; sw += e*hwb[u*256+c];
    }
    float lg = hwb[(t+1)*256+c] + sw/se + bv;
    y[(b*64+t)*256+c] = 1.f/(1.f+__expf(-lg));
  }
}

extern "C" void kernel_launch(void* const* d_in, const int* in_sizes, int n_in,
                              void* d_out, int out_size, void* d_ws, size_t ws_size,
                              hipStream_t stream)
{
  (void)in_sizes; (void)n_in; (void)out_size; (void)ws_size;
  const int*   q      = (const int*)  d_in[0];
  const int*   r      = (const int*)  d_in[1];
  const float* x_emb  = (const float*)d_in[2];
  const float* q_emb  = (const float*)d_in[3];
  const float* init_h = (const float*)d_in[4];
  const float* w1     = (const float*)d_in[5];
  const float* b1     = (const float*)d_in[6];
  const float* w2     = (const float*)d_in[7];
  const float* b2     = (const float*)d_in[8];
  const float* w_ih   = (const float*)d_in[9];
  const float* w_hh   = (const float*)d_in[10];
  const float* b_ih   = (const float*)d_in[11];
  const float* b_hh   = (const float*)d_in[12];
  const float* bias   = (const float*)d_in[13];
  const float* out_w  = (const float*)d_in[14];
  const float* theta  = (const float*)d_in[15];

  float* out    = (float*)d_out;
  float* y      = out;
  float* h_full = out + 262144;
  float* ws     = (float*)d_ws;

  hipMemsetAsync((unsigned*)ws + WS_GFLAG, 0, 64*sizeof(unsigned), stream);
  kPrep<<<1681,256,0,stream>>>(q,r,x_emb,q_emb,init_h,w1,b1,w2,b2,w_ih,w_hh,b_ih,b_hh,ws,h_full);
  {
    hipFuncSetAttribute((const void*)kW, hipFuncAttributeMaxDynamicSharedMemorySize, LDSBYTES);
    void* ka[] = { (void*)&q, (void*)&b_hh, (void*)&init_h, (void*)&ws, (void*)&h_full };
    hipError_t e = hipLaunchCooperativeKernel((const void*)kW, dim3(64), dim3(192), ka, LDSBYTES, stream);
    if (e != hipSuccess) {
      kW<<<dim3(64),dim3(192),LDSBYTES,stream>>>(q,b_hh,init_h,ws,h_full);
    }
  }
  kHw<<<1040,256,0,stream>>>(h_full, out_w, ws + WS_HW);
  kY<<<64,256,0,stream>>>(q, ws, bias, theta, y);
}